// Round 1
// baseline (980.799 us; speedup 1.0000x reference)
//
#include <hip/hip_runtime.h>
#include <math.h>
#include <stdint.h>

#define LOG2_T 19
#define T_SIZE (1u << LOG2_T)
#define T_MASK (T_SIZE - 1u)
#define N_LEVELS 16
#define PRIME1 2654435761u
#define PRIME2 805459861u

struct ResArgs { int r[N_LEVELS]; };

// One thread per (point, level). threadIdx.x = p*16 + l  (l in low bits so the
// float2 output stores are wave-coalesced: 64 lanes -> 512B contiguous).
__global__ __launch_bounds__(256) void hashgrid_fwd(
    const float* __restrict__ x,      // [N, 3]
    const float* __restrict__ emb,    // [16, T, 2]
    float* __restrict__ out,          // [N, 32]
    int N, ResArgs res)
{
    __shared__ float xs[16 * 3];

    const int tid = threadIdx.x;
    const int block_pt = blockIdx.x * 16;

    // Stage this block's 16 points (48 floats) into LDS, coalesced.
    if (tid < 48) {
        int g = block_pt * 3 + tid;
        xs[tid] = (g < N * 3) ? x[g] : 0.0f;
    }
    __syncthreads();

    const int p = tid >> 4;      // point within block
    const int l = tid & 15;      // level
    const int n = block_pt + p;
    if (n >= N) return;

    const int   rl = res.r[l];
    const float rf = (float)(rl - 1);

    float sx = xs[p * 3 + 0] * rf;
    float sy = xs[p * 3 + 1] * rf;
    float sz = xs[p * 3 + 2] * rf;

    int ix = (int)sx; ix = ix < 0 ? 0 : (ix > rl - 2 ? rl - 2 : ix);
    int iy = (int)sy; iy = iy < 0 ? 0 : (iy > rl - 2 ? rl - 2 : iy);
    int iz = (int)sz; iz = iz < 0 ? 0 : (iz > rl - 2 ? rl - 2 : iz);

    const float fx = sx - (float)ix;
    const float fy = sy - (float)iy;
    const float fz = sz - (float)iz;

    // Hash components. dim0 uses prime 1 (identity); corner+1 in a dim just
    // adds the prime (uint32 wraparound matches reference's low-bit math).
    const uint32_t hx0 = (uint32_t)ix,          hx1 = hx0 + 1u;
    const uint32_t hy0 = (uint32_t)iy * PRIME1, hy1 = hy0 + PRIME1;
    const uint32_t hz0 = (uint32_t)iz * PRIME2, hz1 = hz0 + PRIME2;

    const float2* __restrict__ tab = (const float2*)emb + (size_t)l * T_SIZE;

    // corner bit0 -> x, bit1 -> y, bit2 -> z
    uint32_t h0 = (hx0 ^ hy0 ^ hz0) & T_MASK;
    uint32_t h1 = (hx1 ^ hy0 ^ hz0) & T_MASK;
    uint32_t h2 = (hx0 ^ hy1 ^ hz0) & T_MASK;
    uint32_t h3 = (hx1 ^ hy1 ^ hz0) & T_MASK;
    uint32_t h4 = (hx0 ^ hy0 ^ hz1) & T_MASK;
    uint32_t h5 = (hx1 ^ hy0 ^ hz1) & T_MASK;
    uint32_t h6 = (hx0 ^ hy1 ^ hz1) & T_MASK;
    uint32_t h7 = (hx1 ^ hy1 ^ hz1) & T_MASK;

    // Issue all 8 gathers up front so they overlap.
    float2 e0 = tab[h0];
    float2 e1 = tab[h1];
    float2 e2 = tab[h2];
    float2 e3 = tab[h3];
    float2 e4 = tab[h4];
    float2 e5 = tab[h5];
    float2 e6 = tab[h6];
    float2 e7 = tab[h7];

    const float wx0 = 1.0f - fx, wx1 = fx;
    const float wy0 = 1.0f - fy, wy1 = fy;
    const float wz0 = 1.0f - fz, wz1 = fz;

    float w, f0 = 0.0f, f1 = 0.0f;
    w = wx0 * wy0 * wz0; f0 = fmaf(w, e0.x, f0); f1 = fmaf(w, e0.y, f1);
    w = wx1 * wy0 * wz0; f0 = fmaf(w, e1.x, f0); f1 = fmaf(w, e1.y, f1);
    w = wx0 * wy1 * wz0; f0 = fmaf(w, e2.x, f0); f1 = fmaf(w, e2.y, f1);
    w = wx1 * wy1 * wz0; f0 = fmaf(w, e3.x, f0); f1 = fmaf(w, e3.y, f1);
    w = wx0 * wy0 * wz1; f0 = fmaf(w, e4.x, f0); f1 = fmaf(w, e4.y, f1);
    w = wx1 * wy0 * wz1; f0 = fmaf(w, e5.x, f0); f1 = fmaf(w, e5.y, f1);
    w = wx0 * wy1 * wz1; f0 = fmaf(w, e6.x, f0); f1 = fmaf(w, e6.y, f1);
    w = wx1 * wy1 * wz1; f0 = fmaf(w, e7.x, f0); f1 = fmaf(w, e7.y, f1);

    float2 o; o.x = f0; o.y = f1;
    ((float2*)out)[(size_t)n * N_LEVELS + l] = o;
}

extern "C" void kernel_launch(void* const* d_in, const int* in_sizes, int n_in,
                              void* d_out, int out_size, void* d_ws, size_t ws_size,
                              hipStream_t stream) {
    const float* x   = (const float*)d_in[0];
    const float* emb = (const float*)d_in[1];
    float* out = (float*)d_out;
    const int N = in_sizes[0] / 3;

    // Replicate CPython's int(16 * b**i) with the same libm call sequence so
    // truncation-sensitive levels (16*b^3 ~= 32.0) match bit-exactly.
    ResArgs res;
    const double b = exp((log(512.0) - log(16.0)) / 15.0);
    for (int i = 0; i < N_LEVELS; ++i)
        res.r[i] = (int)(16.0 * pow(b, (double)i));

    const int blocks = (N + 15) / 16;
    hipLaunchKernelGGL(hashgrid_fwd, dim3(blocks), dim3(256), 0, stream,
                       x, emb, out, N, res);
}

// Round 2
// 834.052 us; speedup vs baseline: 1.1759x; 1.1759x over previous
//
#include <hip/hip_runtime.h>
#include <math.h>
#include <stdint.h>

#define LOG2_T 19
#define T_SIZE (1u << LOG2_T)
#define T_MASK (T_SIZE - 1u)
#define N_LEVELS 16
#define PRIME1 2654435761u
#define PRIME2 805459861u

struct ResArgs { int r[N_LEVELS]; };

// ---------- helpers: packed bf16x2 (feature0 in low 16, feature1 in high 16) ----------
__device__ __forceinline__ float bf_lo(uint32_t v) { return __uint_as_float(v << 16); }
__device__ __forceinline__ float bf_hi(uint32_t v) { return __uint_as_float(v & 0xFFFF0000u); }

__device__ __forceinline__ uint32_t f32_to_bf16_rne(float f) {
    uint32_t u = __float_as_uint(f);
    // round-to-nearest-even (values are tiny finite floats; no NaN handling needed)
    u += 0x7FFFu + ((u >> 16) & 1u);
    return u >> 16;
}

// ---------- phase 0: convert fp32 table -> packed bf16x2 table in ws ----------
// emb: [16, T, 2] fp32 ; tab: [16, T] uint32 (bf16 pair)
__global__ __launch_bounds__(256) void hg_convert(
    const float2* __restrict__ emb, uint32_t* __restrict__ tab, int n_entries)
{
    int i = blockIdx.x * 256 + threadIdx.x;
    if (i >= n_entries) return;
    float2 e = emb[i];
    tab[i] = f32_to_bf16_rne(e.x) | (f32_to_bf16_rne(e.y) << 16);
}

// ---------- phase 1: level-partitioned gather+blend, level-major output ----------
// blockIdx = chunk*16 + level  =>  blockIdx % 8 == level % 8, so under the
// round-robin block->XCD dispatch each XCD's L2 only sees levels {k, k+8}
// (~2 MB + ~2 MB bf16 line footprint ~= one 4 MB XCD L2).
__global__ __launch_bounds__(256) void hg_levels(
    const float* __restrict__ x,        // [N, 3]
    const uint32_t* __restrict__ tab,   // [16, T] packed bf16x2
    float2* __restrict__ feat,          // [16, N] level-major intermediate
    int N, ResArgs res)
{
    const int l = blockIdx.x & 15;
    const int n = (blockIdx.x >> 4) * 256 + threadIdx.x;
    if (n >= N) return;

    const int   rl = res.r[l];
    const float rf = (float)(rl - 1);

    const float sx = x[n * 3 + 0] * rf;
    const float sy = x[n * 3 + 1] * rf;
    const float sz = x[n * 3 + 2] * rf;

    int ix = (int)sx; ix = ix < 0 ? 0 : (ix > rl - 2 ? rl - 2 : ix);
    int iy = (int)sy; iy = iy < 0 ? 0 : (iy > rl - 2 ? rl - 2 : iy);
    int iz = (int)sz; iz = iz < 0 ? 0 : (iz > rl - 2 ? rl - 2 : iz);

    const float fx = sx - (float)ix;
    const float fy = sy - (float)iy;
    const float fz = sz - (float)iz;

    const uint32_t hx0 = (uint32_t)ix,          hx1 = hx0 + 1u;
    const uint32_t hy0 = (uint32_t)iy * PRIME1, hy1 = hy0 + PRIME1;
    const uint32_t hz0 = (uint32_t)iz * PRIME2, hz1 = hz0 + PRIME2;

    const uint32_t* __restrict__ t = tab + (size_t)l * T_SIZE;

    const uint32_t h0 = (hx0 ^ hy0 ^ hz0) & T_MASK;
    const uint32_t h1 = (hx1 ^ hy0 ^ hz0) & T_MASK;
    const uint32_t h2 = (hx0 ^ hy1 ^ hz0) & T_MASK;
    const uint32_t h3 = (hx1 ^ hy1 ^ hz0) & T_MASK;
    const uint32_t h4 = (hx0 ^ hy0 ^ hz1) & T_MASK;
    const uint32_t h5 = (hx1 ^ hy0 ^ hz1) & T_MASK;
    const uint32_t h6 = (hx0 ^ hy1 ^ hz1) & T_MASK;
    const uint32_t h7 = (hx1 ^ hy1 ^ hz1) & T_MASK;

    // 8 independent 4 B gathers, all in flight together
    const uint32_t e0 = t[h0];
    const uint32_t e1 = t[h1];
    const uint32_t e2 = t[h2];
    const uint32_t e3 = t[h3];
    const uint32_t e4 = t[h4];
    const uint32_t e5 = t[h5];
    const uint32_t e6 = t[h6];
    const uint32_t e7 = t[h7];

    const float wx0 = 1.0f - fx, wx1 = fx;
    const float wy0 = 1.0f - fy, wy1 = fy;
    const float wz0 = 1.0f - fz, wz1 = fz;

    float w, f0 = 0.0f, f1 = 0.0f;
    w = wx0 * wy0 * wz0; f0 = fmaf(w, bf_lo(e0), f0); f1 = fmaf(w, bf_hi(e0), f1);
    w = wx1 * wy0 * wz0; f0 = fmaf(w, bf_lo(e1), f0); f1 = fmaf(w, bf_hi(e1), f1);
    w = wx0 * wy1 * wz0; f0 = fmaf(w, bf_lo(e2), f0); f1 = fmaf(w, bf_hi(e2), f1);
    w = wx1 * wy1 * wz0; f0 = fmaf(w, bf_lo(e3), f0); f1 = fmaf(w, bf_hi(e3), f1);
    w = wx0 * wy0 * wz1; f0 = fmaf(w, bf_lo(e4), f0); f1 = fmaf(w, bf_hi(e4), f1);
    w = wx1 * wy0 * wz1; f0 = fmaf(w, bf_lo(e5), f0); f1 = fmaf(w, bf_hi(e5), f1);
    w = wx0 * wy1 * wz1; f0 = fmaf(w, bf_lo(e6), f0); f1 = fmaf(w, bf_hi(e6), f1);
    w = wx1 * wy1 * wz1; f0 = fmaf(w, bf_lo(e7), f0); f1 = fmaf(w, bf_hi(e7), f1);

    float2 o; o.x = f0; o.y = f1;
    feat[(size_t)l * N + n] = o;   // coalesced: consecutive lanes, consecutive n
}

// ---------- phase 2: transpose [16, N] -> [N, 16] float2 ----------
// Reads coalesced per level; each thread then owns one point's 128 B row and
// writes it as 8 float4 stores (every byte written once; L2 write-combines).
__global__ __launch_bounds__(256) void hg_transpose(
    const float2* __restrict__ feat, float4* __restrict__ out, int N)
{
    int n = blockIdx.x * 256 + threadIdx.x;
    if (n >= N) return;
    float2 v[N_LEVELS];
#pragma unroll
    for (int l = 0; l < N_LEVELS; ++l) v[l] = feat[(size_t)l * N + n];
#pragma unroll
    for (int k = 0; k < 8; ++k) {
        float4 o; o.x = v[2 * k].x; o.y = v[2 * k].y; o.z = v[2 * k + 1].x; o.w = v[2 * k + 1].y;
        out[(size_t)n * 8 + k] = o;
    }
}

// ---------- fallback (round-1 kernel): used only if ws is too small ----------
__global__ __launch_bounds__(256) void hg_fallback(
    const float* __restrict__ x, const float* __restrict__ emb,
    float* __restrict__ out, int N, ResArgs res)
{
    __shared__ float xs[16 * 3];
    const int tid = threadIdx.x;
    const int block_pt = blockIdx.x * 16;
    if (tid < 48) {
        int g = block_pt * 3 + tid;
        xs[tid] = (g < N * 3) ? x[g] : 0.0f;
    }
    __syncthreads();
    const int p = tid >> 4, l = tid & 15, n = block_pt + p;
    if (n >= N) return;
    const int rl = res.r[l];
    const float rf = (float)(rl - 1);
    float sx = xs[p * 3 + 0] * rf, sy = xs[p * 3 + 1] * rf, sz = xs[p * 3 + 2] * rf;
    int ix = (int)sx; ix = ix < 0 ? 0 : (ix > rl - 2 ? rl - 2 : ix);
    int iy = (int)sy; iy = iy < 0 ? 0 : (iy > rl - 2 ? rl - 2 : iy);
    int iz = (int)sz; iz = iz < 0 ? 0 : (iz > rl - 2 ? rl - 2 : iz);
    const float fx = sx - ix, fy = sy - iy, fz = sz - iz;
    const uint32_t hx0 = (uint32_t)ix, hx1 = hx0 + 1u;
    const uint32_t hy0 = (uint32_t)iy * PRIME1, hy1 = hy0 + PRIME1;
    const uint32_t hz0 = (uint32_t)iz * PRIME2, hz1 = hz0 + PRIME2;
    const float2* tab = (const float2*)emb + (size_t)l * T_SIZE;
    uint32_t h0 = (hx0 ^ hy0 ^ hz0) & T_MASK, h1 = (hx1 ^ hy0 ^ hz0) & T_MASK;
    uint32_t h2 = (hx0 ^ hy1 ^ hz0) & T_MASK, h3 = (hx1 ^ hy1 ^ hz0) & T_MASK;
    uint32_t h4 = (hx0 ^ hy0 ^ hz1) & T_MASK, h5 = (hx1 ^ hy0 ^ hz1) & T_MASK;
    uint32_t h6 = (hx0 ^ hy1 ^ hz1) & T_MASK, h7 = (hx1 ^ hy1 ^ hz1) & T_MASK;
    float2 e0 = tab[h0], e1 = tab[h1], e2 = tab[h2], e3 = tab[h3];
    float2 e4 = tab[h4], e5 = tab[h5], e6 = tab[h6], e7 = tab[h7];
    const float wx0 = 1.0f - fx, wx1 = fx, wy0 = 1.0f - fy, wy1 = fy, wz0 = 1.0f - fz, wz1 = fz;
    float w, f0 = 0.0f, f1 = 0.0f;
    w = wx0 * wy0 * wz0; f0 = fmaf(w, e0.x, f0); f1 = fmaf(w, e0.y, f1);
    w = wx1 * wy0 * wz0; f0 = fmaf(w, e1.x, f0); f1 = fmaf(w, e1.y, f1);
    w = wx0 * wy1 * wz0; f0 = fmaf(w, e2.x, f0); f1 = fmaf(w, e2.y, f1);
    w = wx1 * wy1 * wz0; f0 = fmaf(w, e3.x, f0); f1 = fmaf(w, e3.y, f1);
    w = wx0 * wy0 * wz1; f0 = fmaf(w, e4.x, f0); f1 = fmaf(w, e4.y, f1);
    w = wx1 * wy0 * wz1; f0 = fmaf(w, e5.x, f0); f1 = fmaf(w, e5.y, f1);
    w = wx0 * wy1 * wz1; f0 = fmaf(w, e6.x, f0); f1 = fmaf(w, e6.y, f1);
    w = wx1 * wy1 * wz1; f0 = fmaf(w, e7.x, f0); f1 = fmaf(w, e7.y, f1);
    float2 o; o.x = f0; o.y = f1;
    ((float2*)out)[(size_t)n * N_LEVELS + l] = o;
}

extern "C" void kernel_launch(void* const* d_in, const int* in_sizes, int n_in,
                              void* d_out, int out_size, void* d_ws, size_t ws_size,
                              hipStream_t stream) {
    const float* x   = (const float*)d_in[0];
    const float* emb = (const float*)d_in[1];
    const int N = in_sizes[0] / 3;

    // CPython-identical level resolutions (truncation-sensitive at 16*b^3 == 32)
    ResArgs res;
    const double b = exp((log(512.0) - log(16.0)) / 15.0);
    for (int i = 0; i < N_LEVELS; ++i)
        res.r[i] = (int)(16.0 * pow(b, (double)i));

    const size_t tab_bytes  = (size_t)N_LEVELS * T_SIZE * sizeof(uint32_t);   // 32 MB
    const size_t feat_bytes = (size_t)N_LEVELS * N * sizeof(float2);          // 128 MB

    if (ws_size >= tab_bytes + feat_bytes) {
        uint32_t* tab = (uint32_t*)d_ws;
        float2* feat  = (float2*)((char*)d_ws + tab_bytes);

        const int n_entries = N_LEVELS * T_SIZE;   // 8M packed bf16x2 entries
        hipLaunchKernelGGL(hg_convert, dim3((n_entries + 255) / 256), dim3(256), 0, stream,
                           (const float2*)emb, tab, n_entries);

        const int chunks = (N + 255) / 256;
        hipLaunchKernelGGL(hg_levels, dim3(chunks * N_LEVELS), dim3(256), 0, stream,
                           x, tab, feat, N, res);

        hipLaunchKernelGGL(hg_transpose, dim3((N + 255) / 256), dim3(256), 0, stream,
                           feat, (float4*)d_out, N);
    } else {
        hipLaunchKernelGGL(hg_fallback, dim3((N + 15) / 16), dim3(256), 0, stream,
                           x, emb, (float*)d_out, N, res);
    }
}

// Round 3
// 502.922 us; speedup vs baseline: 1.9502x; 1.6584x over previous
//
#include <hip/hip_runtime.h>
#include <math.h>
#include <stdint.h>

#define LOG2_T 19
#define T_SIZE (1u << LOG2_T)
#define T_MASK (T_SIZE - 1u)
#define N_LEVELS 16
#define N_DENSE 8            // levels 0..7 use dense brick tables (res^3 <= T)
#define PRIME1 2654435761u
#define PRIME2 805459861u

typedef unsigned long long u64;
typedef float f4v __attribute__((ext_vector_type(4)));

struct Params {
    int res[N_LEVELS];
    int brick[N_DENSE];      // B = (res+1)/2 : bricks per axis
    int off[N_DENSE];        // entry offset of each dense level table
    int dense_total;         // total dense entries
};

__device__ __forceinline__ float bf_lo(uint32_t v) { return __uint_as_float(v << 16); }
__device__ __forceinline__ float bf_hi(uint32_t v) { return __uint_as_float(v & 0xFFFF0000u); }

__device__ __forceinline__ uint32_t f32_to_bf16_rne(float f) {
    uint32_t u = __float_as_uint(f);
    u += 0x7FFFu + ((u >> 16) & 1u);
    return u >> 16;
}
__device__ __forceinline__ uint32_t pack2(float2 e) {
    return f32_to_bf16_rne(e.x) | (f32_to_bf16_rne(e.y) << 16);
}

__device__ __forceinline__ void nt_store_f2(float2 v, float2* p) {
    union { float2 f; u64 u; } cv; cv.f = v;
    __builtin_nontemporal_store(cv.u, (u64*)p);
}
__device__ __forceinline__ float2 nt_load_f2(const float2* p) {
    union { float2 f; u64 u; } cv;
    cv.u = __builtin_nontemporal_load((const u64*)p);
    return cv.f;
}

// pair load from a hash table: h0 already masked; ix even guarantees the two
// x-corners are entries (h0, h0^1) = one aligned 8B pair.
__device__ __forceinline__ void pair_load(const uint32_t* __restrict__ t,
                                          uint32_t h0, uint32_t& e0, uint32_t& e1) {
    const uint2 q = *(const uint2*)(t + (h0 & ~1u));
    const bool hi = (h0 & 1u);
    e0 = hi ? q.y : q.x;
    e1 = hi ? q.x : q.y;
}

// ---------- build: fine hash tables (levels 8..15) fp32 -> packed bf16 ----------
__global__ __launch_bounds__(256) void hg_build_fine(
    const float2* __restrict__ emb, uint32_t* __restrict__ tabF)
{
    const int i = blockIdx.x * 256 + threadIdx.x;          // [0, 8*T)
    tabF[i] = pack2(emb[(size_t)N_DENSE * T_SIZE + i]);
}

// ---------- build: dense brick tables (levels 0..7) ----------
// entry -> (level, brick, sub) -> cell coords -> reference hash -> gather+pack.
// Identical values to the hash lookup, just re-laid-out for locality.
__global__ __launch_bounds__(256) void hg_build_dense(
    const float2* __restrict__ emb, uint32_t* __restrict__ tabD, Params P)
{
    const int i = blockIdx.x * 256 + threadIdx.x;
    if (i >= P.dense_total) return;
    int l = 0;
    while (l < N_DENSE - 1 && i >= P.off[l + 1]) ++l;
    const int e = i - P.off[l];
    const int B = P.brick[l], R = P.res[l];
    const int sub = e & 7, br = e >> 3;
    int bx = br % B; int t2 = br / B; int by = t2 % B; int bz = t2 / B;
    int x = bx * 2 + (sub & 1);        if (x > R - 1) x = R - 1;   // pad cells unused
    int y = by * 2 + ((sub >> 1) & 1); if (y > R - 1) y = R - 1;
    int z = bz * 2 + (sub >> 2);       if (z > R - 1) z = R - 1;
    const uint32_t h = ((uint32_t)x ^ ((uint32_t)y * PRIME1) ^ ((uint32_t)z * PRIME2)) & T_MASK;
    tabD[i] = pack2(emb[(size_t)l * T_SIZE + h]);
}

// ---------- phase 1: gather + trilinear blend, level-major output ----------
// blockIdx = chunk*16 + level  =>  blockIdx%8 == level%8 : each XCD's L2 sees
// only levels {k, k+8} (~dense(k) + 2MB fine = ~L2 sized).
__global__ __launch_bounds__(256) void hg_levels(
    const float* __restrict__ x,
    const uint32_t* __restrict__ tabF,   // [8, T] packed bf16x2 (levels 8..15)
    const uint32_t* __restrict__ tabD,   // dense brick tables (levels 0..7)
    float2* __restrict__ feat,           // [16, N]
    int N, Params P)
{
    const int l = blockIdx.x & 15;
    const int n = (blockIdx.x >> 4) * 256 + threadIdx.x;
    if (n >= N) return;

    const int   rl = P.res[l];
    const float rf = (float)(rl - 1);

    const float sx = x[n * 3 + 0] * rf;
    const float sy = x[n * 3 + 1] * rf;
    const float sz = x[n * 3 + 2] * rf;

    int ix = (int)sx; ix = ix < 0 ? 0 : (ix > rl - 2 ? rl - 2 : ix);
    int iy = (int)sy; iy = iy < 0 ? 0 : (iy > rl - 2 ? rl - 2 : iy);
    int iz = (int)sz; iz = iz < 0 ? 0 : (iz > rl - 2 ? rl - 2 : iz);

    const float fx = sx - (float)ix;
    const float fy = sy - (float)iy;
    const float fz = sz - (float)iz;

    // c[k]: packed entry for corner k = dx + 2*dy + 4*dz
    uint32_t c0, c1, c2, c3, c4, c5, c6, c7;

    if (l >= N_DENSE) {
        const uint32_t* __restrict__ t = tabF + (size_t)(l - N_DENSE) * T_SIZE;
        const uint32_t hx0 = (uint32_t)ix;
        const uint32_t m00 = ((uint32_t)iy * PRIME1) ^ ((uint32_t)iz * PRIME2);
        const uint32_t m10 = m00 ^ PRIME1;               // dy=1
        const uint32_t m01 = m00 ^ ((uint32_t)iz * PRIME2) ^ (((uint32_t)iz + 1u) * PRIME2); // recompute below instead
        // (recompute cleanly; XOR doesn't distribute over +)
        const uint32_t hy0 = (uint32_t)iy * PRIME1, hy1 = hy0 + PRIME1;
        const uint32_t hz0 = (uint32_t)iz * PRIME2, hz1 = hz0 + PRIME2;
        const uint32_t n00 = hy0 ^ hz0, n10 = hy1 ^ hz0, n01 = hy0 ^ hz1, n11 = hy1 ^ hz1;
        if ((ix & 1) == 0) {
            pair_load(t, (hx0 ^ n00) & T_MASK, c0, c1);
            pair_load(t, (hx0 ^ n10) & T_MASK, c2, c3);
            pair_load(t, (hx0 ^ n01) & T_MASK, c4, c5);
            pair_load(t, (hx0 ^ n11) & T_MASK, c6, c7);
        } else {
            const uint32_t hx1 = hx0 + 1u;
            c0 = t[(hx0 ^ n00) & T_MASK]; c1 = t[(hx1 ^ n00) & T_MASK];
            c2 = t[(hx0 ^ n10) & T_MASK]; c3 = t[(hx1 ^ n10) & T_MASK];
            c4 = t[(hx0 ^ n01) & T_MASK]; c5 = t[(hx1 ^ n01) & T_MASK];
            c6 = t[(hx0 ^ n11) & T_MASK]; c7 = t[(hx1 ^ n11) & T_MASK];
        }
    } else {
        const uint32_t* __restrict__ t = tabD + P.off[l];
        const int B = P.brick[l];
        const int bx0 = ix >> 1, sx0 = ix & 1;
        const int by0 = iy >> 1, sy0 = iy & 1, by1 = (iy + 1) >> 1, sy1 = (iy + 1) & 1;
        const int bz0 = iz >> 1, sz0 = iz & 1, bz1 = (iz + 1) >> 1, sz1 = (iz + 1) & 1;
        // zy term for the 4 (dy,dz) combos: brick row base + sub bits for y,z
        const int zy00 = (((bz0 * B + by0) * B) << 3) | (sy0 << 1) | (sz0 << 2);
        const int zy10 = (((bz0 * B + by1) * B) << 3) | (sy1 << 1) | (sz0 << 2);
        const int zy01 = (((bz1 * B + by0) * B) << 3) | (sy0 << 1) | (sz1 << 2);
        const int zy11 = (((bz1 * B + by1) * B) << 3) | (sy1 << 1) | (sz1 << 2);
        if (sx0 == 0) {   // both x-corners in same brick, consecutive entries
            const uint2 q0 = *(const uint2*)(t + zy00 + (bx0 << 3));
            const uint2 q1 = *(const uint2*)(t + zy10 + (bx0 << 3));
            const uint2 q2 = *(const uint2*)(t + zy01 + (bx0 << 3));
            const uint2 q3 = *(const uint2*)(t + zy11 + (bx0 << 3));
            c0 = q0.x; c1 = q0.y; c2 = q1.x; c3 = q1.y;
            c4 = q2.x; c5 = q2.y; c6 = q3.x; c7 = q3.y;
        } else {
            const int bx1 = bx0 + 1;
            c0 = t[zy00 + (bx0 << 3) + 1]; c1 = t[zy00 + (bx1 << 3)];
            c2 = t[zy10 + (bx0 << 3) + 1]; c3 = t[zy10 + (bx1 << 3)];
            c4 = t[zy01 + (bx0 << 3) + 1]; c5 = t[zy01 + (bx1 << 3)];
            c6 = t[zy11 + (bx0 << 3) + 1]; c7 = t[zy11 + (bx1 << 3)];
        }
    }

    const float wx0 = 1.0f - fx, wx1 = fx;
    const float wy0 = 1.0f - fy, wy1 = fy;
    const float wz0 = 1.0f - fz, wz1 = fz;

    float w, f0 = 0.0f, f1 = 0.0f;
    w = wx0 * wy0 * wz0; f0 = fmaf(w, bf_lo(c0), f0); f1 = fmaf(w, bf_hi(c0), f1);
    w = wx1 * wy0 * wz0; f0 = fmaf(w, bf_lo(c1), f0); f1 = fmaf(w, bf_hi(c1), f1);
    w = wx0 * wy1 * wz0; f0 = fmaf(w, bf_lo(c2), f0); f1 = fmaf(w, bf_hi(c2), f1);
    w = wx1 * wy1 * wz0; f0 = fmaf(w, bf_lo(c3), f0); f1 = fmaf(w, bf_hi(c3), f1);
    w = wx0 * wy0 * wz1; f0 = fmaf(w, bf_lo(c4), f0); f1 = fmaf(w, bf_hi(c4), f1);
    w = wx1 * wy0 * wz1; f0 = fmaf(w, bf_lo(c5), f0); f1 = fmaf(w, bf_hi(c5), f1);
    w = wx0 * wy1 * wz1; f0 = fmaf(w, bf_lo(c6), f0); f1 = fmaf(w, bf_hi(c6), f1);
    w = wx1 * wy1 * wz1; f0 = fmaf(w, bf_lo(c7), f0); f1 = fmaf(w, bf_hi(c7), f1);

    float2 o; o.x = f0; o.y = f1;
    nt_store_f2(o, &feat[(size_t)l * N + n]);   // write-once: don't pollute L2
}

// ---------- phase 2: LDS-tiled transpose [16,N] -> [N,16] float2 ----------
// 32 points/block. Reads coalesced (32 consecutive n per level row); writes
// one float4 per thread, consecutive -> perfectly coalesced.
__global__ __launch_bounds__(256) void hg_transpose(
    const float2* __restrict__ feat, f4v* __restrict__ out, int N)
{
    __shared__ float2 st[N_LEVELS][33];
    const int base = blockIdx.x * 32;
    const int t = threadIdx.x;
#pragma unroll
    for (int i = 0; i < 2; ++i) {
        const int idx = i * 256 + t;       // 0..511
        const int l = idx >> 5, p = idx & 31;
        const int n = base + p;
        st[l][p] = (n < N) ? nt_load_f2(&feat[(size_t)l * N + n]) : make_float2(0.f, 0.f);
    }
    __syncthreads();
    const int p = t >> 3, k = t & 7;
    const int n = base + p;
    if (n < N) {
        const float2 a = st[2 * k][p], b = st[2 * k + 1][p];
        f4v o; o.x = a.x; o.y = a.y; o.z = b.x; o.w = b.y;
        __builtin_nontemporal_store(o, &out[(size_t)n * 8 + k]);
    }
}

// ---------- fallback (round-1 kernel): used only if ws is too small ----------
__global__ __launch_bounds__(256) void hg_fallback(
    const float* __restrict__ x, const float* __restrict__ emb,
    float* __restrict__ out, int N, Params P)
{
    const int gid = blockIdx.x * 256 + threadIdx.x;
    const int n = gid >> 4, l = gid & 15;
    if (n >= N) return;
    const int rl = P.res[l];
    const float rf = (float)(rl - 1);
    float sx = x[n * 3 + 0] * rf, sy = x[n * 3 + 1] * rf, sz = x[n * 3 + 2] * rf;
    int ix = (int)sx; ix = ix < 0 ? 0 : (ix > rl - 2 ? rl - 2 : ix);
    int iy = (int)sy; iy = iy < 0 ? 0 : (iy > rl - 2 ? rl - 2 : iy);
    int iz = (int)sz; iz = iz < 0 ? 0 : (iz > rl - 2 ? rl - 2 : iz);
    const float fx = sx - ix, fy = sy - iy, fz = sz - iz;
    const uint32_t hx0 = (uint32_t)ix, hx1 = hx0 + 1u;
    const uint32_t hy0 = (uint32_t)iy * PRIME1, hy1 = hy0 + PRIME1;
    const uint32_t hz0 = (uint32_t)iz * PRIME2, hz1 = hz0 + PRIME2;
    const float2* tab = (const float2*)emb + (size_t)l * T_SIZE;
    float2 e0 = tab[(hx0 ^ hy0 ^ hz0) & T_MASK], e1 = tab[(hx1 ^ hy0 ^ hz0) & T_MASK];
    float2 e2 = tab[(hx0 ^ hy1 ^ hz0) & T_MASK], e3 = tab[(hx1 ^ hy1 ^ hz0) & T_MASK];
    float2 e4 = tab[(hx0 ^ hy0 ^ hz1) & T_MASK], e5 = tab[(hx1 ^ hy0 ^ hz1) & T_MASK];
    float2 e6 = tab[(hx0 ^ hy1 ^ hz1) & T_MASK], e7 = tab[(hx1 ^ hy1 ^ hz1) & T_MASK];
    const float wx0 = 1.0f - fx, wx1 = fx, wy0 = 1.0f - fy, wy1 = fy, wz0 = 1.0f - fz, wz1 = fz;
    float w, f0 = 0.0f, f1 = 0.0f;
    w = wx0 * wy0 * wz0; f0 = fmaf(w, e0.x, f0); f1 = fmaf(w, e0.y, f1);
    w = wx1 * wy0 * wz0; f0 = fmaf(w, e1.x, f0); f1 = fmaf(w, e1.y, f1);
    w = wx0 * wy1 * wz0; f0 = fmaf(w, e2.x, f0); f1 = fmaf(w, e2.y, f1);
    w = wx1 * wy1 * wz0; f0 = fmaf(w, e3.x, f0); f1 = fmaf(w, e3.y, f1);
    w = wx0 * wy0 * wz1; f0 = fmaf(w, e4.x, f0); f1 = fmaf(w, e4.y, f1);
    w = wx1 * wy0 * wz1; f0 = fmaf(w, e5.x, f0); f1 = fmaf(w, e5.y, f1);
    w = wx0 * wy1 * wz1; f0 = fmaf(w, e6.x, f0); f1 = fmaf(w, e6.y, f1);
    w = wx1 * wy1 * wz1; f0 = fmaf(w, e7.x, f0); f1 = fmaf(w, e7.y, f1);
    float2 o; o.x = f0; o.y = f1;
    ((float2*)out)[(size_t)n * N_LEVELS + l] = o;
}

extern "C" void kernel_launch(void* const* d_in, const int* in_sizes, int n_in,
                              void* d_out, int out_size, void* d_ws, size_t ws_size,
                              hipStream_t stream) {
    const float* x   = (const float*)d_in[0];
    const float* emb = (const float*)d_in[1];
    const int N = in_sizes[0] / 3;

    // CPython-identical level resolutions (truncation-sensitive: 16*b^3 == 32)
    Params P;
    const double b = exp((log(512.0) - log(16.0)) / 15.0);
    for (int i = 0; i < N_LEVELS; ++i)
        P.res[i] = (int)(16.0 * pow(b, (double)i));
    int acc = 0;
    for (int i = 0; i < N_DENSE; ++i) {
        P.brick[i] = (P.res[i] + 1) >> 1;
        P.off[i] = acc;
        acc += P.brick[i] * P.brick[i] * P.brick[i] * 8;
    }
    P.dense_total = acc;

    const size_t fine_bytes  = (size_t)N_DENSE * T_SIZE * sizeof(uint32_t);      // 16 MB
    const size_t dense_bytes = ((size_t)acc * sizeof(uint32_t) + 255) & ~255ull; // ~4.2 MB
    const size_t feat_bytes  = (size_t)N_LEVELS * N * sizeof(float2);            // 128 MB

    if (ws_size >= fine_bytes + dense_bytes + feat_bytes) {
        uint32_t* tabF = (uint32_t*)d_ws;
        uint32_t* tabD = (uint32_t*)((char*)d_ws + fine_bytes);
        float2*   feat = (float2*)((char*)d_ws + fine_bytes + dense_bytes);

        hipLaunchKernelGGL(hg_build_fine, dim3(N_DENSE * T_SIZE / 256), dim3(256), 0, stream,
                           (const float2*)emb, tabF);
        hipLaunchKernelGGL(hg_build_dense, dim3((P.dense_total + 255) / 256), dim3(256), 0, stream,
                           (const float2*)emb, tabD, P);

        const int chunks = (N + 255) / 256;
        hipLaunchKernelGGL(hg_levels, dim3(chunks * N_LEVELS), dim3(256), 0, stream,
                           x, tabF, tabD, feat, N, P);

        hipLaunchKernelGGL(hg_transpose, dim3((N + 31) / 32), dim3(256), 0, stream,
                           feat, (f4v*)d_out, N);
    } else {
        hipLaunchKernelGGL(hg_fallback, dim3((N * 16 + 255) / 256), dim3(256), 0, stream,
                           x, emb, (float*)d_out, N, P);
    }
}